// Round 10
// baseline (3585.485 us; speedup 1.0000x reference)
//
#include <hip/hip_runtime.h>
#include <hip/hip_bf16.h>
#include <stdint.h>

#define HIDDEN 4096
#define INTER  14336
#define NSEL   4096

using short8 = __attribute__((ext_vector_type(8))) short;
using f32x4  = __attribute__((ext_vector_type(4))) float;

__device__ __forceinline__ uint16_t f2bf(float f) {
  uint32_t u = __float_as_uint(f);
  uint32_t r = (u + 0x7FFFu + ((u >> 16) & 1u)) >> 16;
  return (uint16_t)r;
}
__device__ __forceinline__ uint32_t pack2(float lo, float hi) {
  return (uint32_t)f2bf(lo) | ((uint32_t)f2bf(hi) << 16);
}

// ---- prep: gather x_sel->bf16 (blocks<NSEL) + cvt Wg,Wu,Wd fp32->bf16 ----
__global__ void prep(const float* __restrict__ x, const int* __restrict__ idx,
                     uint16_t* __restrict__ xs,
                     const float* __restrict__ Wg, uint16_t* __restrict__ w1,
                     const float* __restrict__ Wu, uint16_t* __restrict__ w2,
                     const float* __restrict__ Wd, uint16_t* __restrict__ w3,
                     int ncvt) {
  const int b = blockIdx.x;
  const int t = threadIdx.x;
  if (b < NSEL) {
    const size_t s = (size_t)idx[b] * HIDDEN + (size_t)t * 16;
    const size_t d = (size_t)b * HIDDEN + (size_t)t * 16;
    const float4* sp = (const float4*)(x + s);
    float4 f0 = sp[0], f1 = sp[1], f2 = sp[2], f3 = sp[3];
    uint4 v0, v1;
    v0.x = pack2(f0.x, f0.y); v0.y = pack2(f0.z, f0.w);
    v0.z = pack2(f1.x, f1.y); v0.w = pack2(f1.z, f1.w);
    v1.x = pack2(f2.x, f2.y); v1.y = pack2(f2.z, f2.w);
    v1.z = pack2(f3.x, f3.y); v1.w = pack2(f3.z, f3.w);
    *(uint4*)(xs + d)     = v0;
    *(uint4*)(xs + d + 8) = v1;
    return;
  }
  int cb = b - NSEL;
  const float* src; uint16_t* dst;
  if (cb < ncvt)            { src = Wg; dst = w1; }
  else if (cb < 2 * ncvt)   { src = Wu; dst = w2; cb -= ncvt; }
  else                      { src = Wd; dst = w3; cb -= 2 * ncvt; }
#pragma unroll
  for (int k = 0; k < 8; ++k) {
    const size_t i = (size_t)cb * 16384 + (size_t)k * 2048 + (size_t)t * 8;
    float4 a = *(const float4*)(src + i);
    float4 c = *(const float4*)(src + i + 4);
    uint4 v;
    v.x = pack2(a.x, a.y); v.y = pack2(a.z, a.w);
    v.z = pack2(c.x, c.y); v.w = pack2(c.z, c.w);
    *(uint4*)(dst + i) = v;
  }
}

__device__ __forceinline__ void gload16(const void* g, void* l) {
  __builtin_amdgcn_global_load_lds(
      (const __attribute__((address_space(1))) void*)g,
      (__attribute__((address_space(3))) void*)l, 16, 0, 0);
}

__device__ __forceinline__ float silu(float g) {
  return g / (1.f + __expf(-g));
}

// ============================================================================
// Fused NT GEMM, A-DIRECT variant. r9 showed the LDS pipe at ~80% busy
// (reads 1.38M + staging 0.34M cyc/CU vs MFMA 1.11M): A is therefore NOT
// staged in LDS anymore. Each wave loads its own A fragments straight from
// global (per-lane 16B, L1-served: a 16KB A-slice/tile is shared by 4 waves
// and bm-slices are L3-resident). LDS holds only B: slot = 16KB, ring-3 =
// 48KB. LDS traffic halves; MFMA becomes the top pipe.
// 1024 threads = 16 waves of 64x64, acc 4x4 f32x4 (64 AGPR), 16 waves/CU.
// MODE 0 (gate+up): BM=256, BN_out=128, TWO B panels (Wg,Wu 128 rows each);
//   wave (s=w>>3, wm=w&3, wn=(w>>2)&1); epilogue g/u exchange through LDS
//   (bank-spread perm), h = silu(g)*u -> bf16 G.
// MODE 1 (down): BM=256, BN=256 single panel; out = acc*Wt[row], NT store.
// Schedule (r6/r9-proven free-run): per tile {A(t) direct loads x4 ->
// stage B(t+2) -> s_waitcnt vmcnt( pre ? 1 : 0 ) [drains B(t+1)=oldest and
// A(t); leaves only B(t+2)] -> ds_read B(t) -> setprio(1) 16 MFMA
// setprio(0) -> s_barrier}. Compiler inserts its own waits before av use.
// B LDS swizzle (r2/r3/r6/r9 measured-ZERO conflicts): line = 2 rows x 32
// cols = 128B; slot16 = (((r&1)<<2)|lg) ^ ((r>>1)&7); inverse-swizzled
// global source + LINEAR gload_lds dest (rule 21).
// T1 bijective XCD swizzle, bm-fastest (blocks on an XCD share B panels).
// ============================================================================
template<int MODE>
__global__ __launch_bounds__(1024, 4) void gemm_f(
    const uint16_t* __restrict__ A,
    const uint16_t* __restrict__ B0,
    const uint16_t* __restrict__ B1,
    uint16_t* __restrict__ G,
    float* __restrict__ O,
    const float* __restrict__ Wt,
    int N, int K)
{
  __shared__ __align__(16) uint16_t lds[3][8192];   // B only: 16KB per slot

  const int nwg = (int)gridDim.x;
  const int bid = (int)blockIdx.x;
  const int lid = (bid & 7) * (nwg >> 3) + (bid >> 3);
  const int bm = lid & 15, bn = lid >> 4;           // nbm = 16 always

  const int tid  = (int)threadIdx.x;
  const int lane = tid & 63, w = tid >> 6;
  const int lr = lane & 15, lg = lane >> 4;

  int wm, wn, s;
  if constexpr (MODE == 0) { s = w >> 3; wm = w & 3; wn = (w >> 2) & 1; }
  else                     { s = 0;      wm = w & 3; wn = w >> 2;       }

  // ---- A: direct per-lane global pointers (row-major, 16B per frag) ----
  const uint16_t* aBase = A + (size_t)(bm * 256 + wm * 64 + lr) * K + lg * 8;
  const size_t aMstep = (size_t)16 * K;   // 16 rows

  // ---- B fragment read offsets (u16, slot-relative), proven-zero swizzle ----
  int offB[4];
  const int bBase = (MODE == 0) ? s * 4096 : 0;
#pragma unroll
  for (int n = 0; n < 4; ++n) {
    const int r = wn * 64 + n * 16 + lr;
    offB[n] = bBase + (r >> 1) * 64 + (((((r & 1) << 2) | lg) ^ ((r >> 1) & 7)) * 8);
  }

  // ---- B staging (inverse-swizzled global source, linear gload_lds dest) ----
  // MODE0: tid<512 -> Wg panel, tid>=512 -> Wu panel (j = tid&511, 128 rows).
  // MODE1: all 1024 threads, 256 rows.
  const int jB    = (MODE == 0) ? (tid & 511) : tid;
  const int suB   = (jB & 7) ^ ((jB >> 3) & 7);
  const int sRowB = 2 * (jB >> 3) + (suB >> 2);
  const int sColB = (suB & 3) * 8;
  const uint16_t* bSel = (MODE == 0) ? ((tid < 512) ? B0 : B1) : B0;
  const uint16_t* bSrc = bSel + (size_t)(bn * ((MODE == 0) ? 128 : 256) + sRowB) * K + sColB;
  const int bDst = (MODE == 0) ? ((tid >> 9) * 4096 + (tid & 511) * 8)
                               : (tid * 8);

#define STAGE_B(tt, sl) gload16(bSrc + (size_t)(tt) * 32, &lds[sl][bDst])

  f32x4 acc[4][4];
#pragma unroll
  for (int m = 0; m < 4; ++m)
#pragma unroll
    for (int n = 0; n < 4; ++n)
#pragma unroll
      for (int j = 0; j < 4; ++j) acc[m][n][j] = 0.f;

  const int nk = K >> 5;

  // prologue: stage B tiles 0,1; certify B0 (B1 stays in flight)
  STAGE_B(0, 0);
  STAGE_B(1, 1);
  asm volatile("s_waitcnt vmcnt(1)" ::: "memory");
  __builtin_amdgcn_s_barrier();

  for (int t = 0; t < nk; ++t) {
    const uint16_t* S = &lds[t % 3][0];

    // A(t) direct loads (compiler adds its own waits before use)
    short8 av[4];
#pragma unroll
    for (int m = 0; m < 4; ++m)
      av[m] = *(const short8*)(aBase + (size_t)m * aMstep + (size_t)t * 32);

    if (t + 2 < nk) STAGE_B(t + 2, (t + 2) % 3);

    // counted wait: drains B(t+1) (oldest) and A(t); leaves only B(t+2).
    // Also fences the ds_reads below from hoisting above this point.
    if (t + 2 < nk) { asm volatile("s_waitcnt vmcnt(1)" ::: "memory"); }
    else            { asm volatile("s_waitcnt vmcnt(0)" ::: "memory"); }

    short8 bv[4];
#pragma unroll
    for (int n = 0; n < 4; ++n) bv[n] = *(const short8*)&S[offB[n]];

    __builtin_amdgcn_s_setprio(1);
#pragma unroll
    for (int m = 0; m < 4; ++m)
#pragma unroll
      for (int n = 0; n < 4; ++n)
        acc[m][n] = __builtin_amdgcn_mfma_f32_16x16x32_bf16(av[m], bv[n], acc[m][n], 0, 0, 0);
    __builtin_amdgcn_s_setprio(0);

    __builtin_amdgcn_s_barrier();
  }
#undef STAGE_B

  // C/D layout: col = lane&15, row = (lane>>4)*4 + reg  [m89-verified]
  if constexpr (MODE == 1) {
    const int row0 = bm * 256 + wm * 64, col0 = bn * 256 + wn * 64;
#pragma unroll
    for (int m = 0; m < 4; ++m)
#pragma unroll
      for (int n = 0; n < 4; ++n) {
        const int c  = col0 + n * 16 + lr;
        const int rb = row0 + m * 16 + lg * 4;
#pragma unroll
        for (int j = 0; j < 4; ++j) {
          const int r = rb + j;
          __builtin_nontemporal_store(acc[m][n][j] * Wt[r], &O[(size_t)r * N + c]);
        }
      }
  } else {
    // g/u exchange through LDS; bank-spread perm (lg ^ ((lr>>1)&3)) keeps
    // each 16-lane quarter-wave on 8 distinct banks (2-way = free).
    float* X = (float*)&lds[0][0];   // 8 g-waves x 4KB = 32KB (loop-dead)
    const int xo = lr * 16 + ((lg ^ ((lr >> 1) & 3)) * 4);
    const int row0 = bm * 256 + wm * 64, col0 = bn * 128 + wn * 64;
#pragma unroll
    for (int m = 0; m < 4; ++m) {
      __builtin_amdgcn_s_barrier();          // prev phase's reads done
      if (s == 0) {
#pragma unroll
        for (int n = 0; n < 4; ++n)
          *(f32x4*)&X[w * 1024 + n * 256 + xo] = acc[m][n];
      }
      __builtin_amdgcn_s_barrier();          // writes visible
      if (s == 1) {
#pragma unroll
        for (int n = 0; n < 4; ++n) {
          const f32x4 g4 = *(const f32x4*)&X[(w - 8) * 1024 + n * 256 + xo];
          const int c  = col0 + n * 16 + lr;
          const int rb = row0 + m * 16 + lg * 4;
#pragma unroll
          for (int j = 0; j < 4; ++j)
            G[(size_t)(rb + j) * N + c] = f2bf(silu(g4[j]) * acc[m][n][j]);
        }
      }
    }
  }
}

extern "C" void kernel_launch(void* const* d_in, const int* in_sizes, int n_in,
                              void* d_out, int out_size, void* d_ws, size_t ws_size,
                              hipStream_t stream) {
  const float* x   = (const float*)d_in[0];
  const float* Wg  = (const float*)d_in[1];
  const float* Wu  = (const float*)d_in[2];
  const float* Wd  = (const float*)d_in[3];
  const int*   top = (const int*)d_in[4];
  const float* wt  = (const float*)d_in[5];
  float* out = (float*)d_out;

  const size_t NE_X = (size_t)NSEL * HIDDEN;
  const size_t NE_W = (size_t)INTER * HIDDEN;
  if (ws_size < (NE_X + 4 * NE_W) * sizeof(uint16_t)) return;

  uint16_t* xs = (uint16_t*)d_ws;
  uint16_t* w1 = xs + NE_X;    // Wg bf16
  uint16_t* w2 = w1 + NE_W;    // Wu bf16
  uint16_t* w3 = w2 + NE_W;    // Wd bf16
  uint16_t* gh = w3 + NE_W;    // h bf16 [NSEL][INTER]

  const int NCVT = (int)(NE_W / 16384);   // 3584 blocks per weight
  const int ngGU = 16 * (INTER / 128);    // 1792
  const int ngDN = 16 * (HIDDEN / 256);   // 256

  // gather + all three weight cvts in one HBM-stream launch
  prep<<<NSEL + 3 * NCVT, 256, 0, stream>>>(x, top, xs, Wg, w1, Wu, w2, Wd, w3, NCVT);

  // fused gate+up: h = silu(x Wg^T) * (x Wu^T) -> gh (bf16)
  gemm_f<0><<<ngGU, 1024, 0, stream>>>(xs, w1, w2, gh, nullptr, nullptr,
                                       INTER, HIDDEN);
  // down + routing weight: out = (h Wd^T) * weight[:,None]
  gemm_f<1><<<ngDN, 1024, 0, stream>>>(gh, w3, nullptr, nullptr, out, wt,
                                       HIDDEN, INTER);
}

// Round 11
// 1396.185 us; speedup vs baseline: 2.5681x; 2.5681x over previous
//
#include <hip/hip_runtime.h>
#include <hip/hip_bf16.h>
#include <stdint.h>

#define HIDDEN 4096
#define INTER  14336
#define NSEL   4096

using short8 = __attribute__((ext_vector_type(8))) short;
using f32x4  = __attribute__((ext_vector_type(4))) float;

__device__ __forceinline__ uint16_t f2bf(float f) {
  uint32_t u = __float_as_uint(f);
  uint32_t r = (u + 0x7FFFu + ((u >> 16) & 1u)) >> 16;
  return (uint16_t)r;
}
__device__ __forceinline__ uint32_t pack2(float lo, float hi) {
  return (uint32_t)f2bf(lo) | ((uint32_t)f2bf(hi) << 16);
}

// ---- prep: gather x_sel->bf16 (blocks<NSEL) + cvt Wg,Wu fp32->bf16 ----
// (Wd conversion rides inside the GU GEMM as tail blocks: GU is LDS-bound
//  with ~5 TB/s of spare HBM; w3 is untouched by prep, consumed next launch.)
__global__ void prep(const float* __restrict__ x, const int* __restrict__ idx,
                     uint16_t* __restrict__ xs,
                     const float* __restrict__ Wg, uint16_t* __restrict__ w1,
                     const float* __restrict__ Wu, uint16_t* __restrict__ w2,
                     int ncvt) {
  const int b = blockIdx.x;
  const int t = threadIdx.x;
  if (b < NSEL) {
    const size_t s = (size_t)idx[b] * HIDDEN + (size_t)t * 16;
    const size_t d = (size_t)b * HIDDEN + (size_t)t * 16;
    const float4* sp = (const float4*)(x + s);
    float4 f0 = sp[0], f1 = sp[1], f2 = sp[2], f3 = sp[3];
    uint4 v0, v1;
    v0.x = pack2(f0.x, f0.y); v0.y = pack2(f0.z, f0.w);
    v0.z = pack2(f1.x, f1.y); v0.w = pack2(f1.z, f1.w);
    v1.x = pack2(f2.x, f2.y); v1.y = pack2(f2.z, f2.w);
    v1.z = pack2(f3.x, f3.y); v1.w = pack2(f3.z, f3.w);
    *(uint4*)(xs + d)     = v0;
    *(uint4*)(xs + d + 8) = v1;
    return;
  }
  int cb = b - NSEL;
  const float* src; uint16_t* dst;
  if (cb < ncvt) { src = Wg; dst = w1; }
  else           { src = Wu; dst = w2; cb -= ncvt; }
#pragma unroll
  for (int k = 0; k < 8; ++k) {
    const size_t i = (size_t)cb * 16384 + (size_t)k * 2048 + (size_t)t * 8;
    float4 a = *(const float4*)(src + i);
    float4 c = *(const float4*)(src + i + 4);
    uint4 v;
    v.x = pack2(a.x, a.y); v.y = pack2(a.z, a.w);
    v.z = pack2(c.x, c.y); v.w = pack2(c.z, c.w);
    *(uint4*)(dst + i) = v;
  }
}

__device__ __forceinline__ void gload16(const void* g, void* l) {
  __builtin_amdgcn_global_load_lds(
      (const __attribute__((address_space(1))) void*)g,
      (__attribute__((address_space(3))) void*)l, 16, 0, 0);
}

__device__ __forceinline__ float silu(float g) {
  return g / (1.f + __expf(-g));
}

// ============================================================================
// Fused NT GEMM — r9 structure (best measured: 1418 µs total), + ring-4
// depth-3 prefetch, + epilogue-exchange bank-spread, + Wd-cvt tail in GU.
// r10's A-direct is REVERTED (latency-bound: 2370 µs, MfmaUtil 17%) — A
// stays in LDS; gload_lds staging is the latency-amortization path.
// 1024 threads = 16 waves of 64x64 (acc 64 AGPR; <=128 regs -> 16 waves/CU,
// the measured occupancy requirement). LDS slot = A 16KB + B 16KB; ring-4
// = 128KB, 1 block/CU. Free-run schedule: per K32-tile {stage t+3 ->
// ds_read(t) -> setprio(1) 16 MFMA setprio(0) -> counted vmcnt certifying
// t+1 (t+2,t+3 stay in flight; never drains mid-loop) -> s_barrier}.
// MODE 0 (gate+up): BM=256, BNout=128, TWO B panels (Wg,Wu 128 rows);
//   wave (s=w>>3, wm=w&3, wn=(w>>2)&1); epilogue: g-waves pass acc via LDS
//   (bank-spread perm: 2-way max) to u-waves -> h = silu(g)*u -> bf16.
//   Tail blocks (bid>=nGemm) convert Wd fp32->bf16 (w3; consumed next
//   launch only -> race-free), using GU's spare HBM bandwidth.
// MODE 1 (down): BM=256, BN=256 single panel; out = acc*Wt[row], NT store.
// LDS swizzle (r2/r3/r6/r9 measured-ZERO): line = 2 rows x 32 cols = 128B;
// slot16 = (((r&1)<<2)|lg) ^ ((r>>1)&7); pre-inverse-swizzled global
// source + LINEAR gload_lds dest (rule 21).
// T1 bijective XCD swizzle over the gemm sub-grid, bm-fastest.
// ============================================================================
template<int MODE>
__global__ __launch_bounds__(1024, 4) void gemm_f(
    const uint16_t* __restrict__ A,
    const uint16_t* __restrict__ B0,
    const uint16_t* __restrict__ B1,
    uint16_t* __restrict__ G,
    float* __restrict__ O,
    const float* __restrict__ Wt,
    int N, int K, int nGemm,
    const float* __restrict__ cvtIn, uint16_t* __restrict__ cvtOut)
{
  __shared__ __align__(16) uint16_t lds[4][16384];  // [slot][A 0..8191 | B 8192..16383]

  const int bid = (int)blockIdx.x;
  const int tid = (int)threadIdx.x;

  // ---- Wd-cvt tail (MODE 0 only): 65536 elems/block, 64/thread ----
  if (MODE == 0 && bid >= nGemm) {
    const int cb = bid - nGemm;
#pragma unroll
    for (int k = 0; k < 8; ++k) {
      const size_t i = (size_t)cb * 65536 + (size_t)k * 8192 + (size_t)tid * 8;
      float4 a = *(const float4*)(cvtIn + i);
      float4 c = *(const float4*)(cvtIn + i + 4);
      uint4 v;
      v.x = pack2(a.x, a.y); v.y = pack2(a.z, a.w);
      v.z = pack2(c.x, c.y); v.w = pack2(c.z, c.w);
      *(uint4*)(cvtOut + i) = v;
    }
    return;
  }

  const int lid = (bid & 7) * (nGemm >> 3) + (bid >> 3);
  const int bm = lid & 15, bn = lid >> 4;           // nbm = 16 always

  const int lane = tid & 63, w = tid >> 6;
  const int lr = lane & 15, lg = lane >> 4;

  int wm, wn, s;
  if constexpr (MODE == 0) { s = w >> 3; wm = w & 3; wn = (w >> 2) & 1; }
  else                     { s = 0;      wm = w & 3; wn = w >> 2;       }

  // ---- fragment read offsets (u16, slot-relative), proven-zero swizzle ----
  int offA[4], offB[4];
#pragma unroll
  for (int m = 0; m < 4; ++m) {
    const int r = wm * 64 + m * 16 + lr;
    offA[m] = (r >> 1) * 64 + (((((r & 1) << 2) | lg) ^ ((r >> 1) & 7)) * 8);
  }
  const int bBase = (MODE == 0) ? (8192 + s * 4096) : 8192;
#pragma unroll
  for (int n = 0; n < 4; ++n) {
    const int r = wn * 64 + n * 16 + lr;
    offB[n] = bBase + (r >> 1) * 64 + (((((r & 1) << 2) | lg) ^ ((r >> 1) & 7)) * 8);
  }

  // ---- staging (inverse-swizzled global source, linear gload_lds dest) ----
  const int suA   = (tid & 7) ^ ((tid >> 3) & 7);
  const int sRowA = 2 * (tid >> 3) + (suA >> 2);
  const int sColA = (suA & 3) * 8;
  const uint16_t* aSrc = A + (size_t)(bm * 256 + sRowA) * K + sColA;

  const int jB    = (MODE == 0) ? (tid & 511) : tid;
  const int suB   = (jB & 7) ^ ((jB >> 3) & 7);
  const int sRowB = 2 * (jB >> 3) + (suB >> 2);
  const int sColB = (suB & 3) * 8;
  const uint16_t* bSel = (MODE == 0) ? ((tid < 512) ? B0 : B1) : B0;
  const uint16_t* bSrc = bSel + (size_t)(bn * ((MODE == 0) ? 128 : 256) + sRowB) * K + sColB;
  const int bDst = (MODE == 0) ? (8192 + (tid >> 9) * 4096 + (tid & 511) * 8)
                               : (8192 + tid * 8);

#define STAGE(tt, sl) do { \
    gload16(aSrc + (size_t)(tt) * 32, &lds[sl][tid * 8]); \
    gload16(bSrc + (size_t)(tt) * 32, &lds[sl][bDst]); \
  } while (0)

  f32x4 acc[4][4];
#pragma unroll
  for (int m = 0; m < 4; ++m)
#pragma unroll
    for (int n = 0; n < 4; ++n)
#pragma unroll
      for (int j = 0; j < 4; ++j) acc[m][n][j] = 0.f;

  const int nk = K >> 5;

  // prologue: stage tiles 0,1,2; certify tile 0 (4 loads stay in flight)
  STAGE(0, 0);
  STAGE(1, 1);
  STAGE(2, 2);
  asm volatile("s_waitcnt vmcnt(4)" ::: "memory");
  __builtin_amdgcn_s_barrier();

  for (int t = 0; t < nk; ++t) {
    const uint16_t* S = &lds[t & 3][0];

    if (t + 3 < nk) STAGE(t + 3, (t + 3) & 3);

    short8 av[4], bv[4];
#pragma unroll
    for (int m = 0; m < 4; ++m) av[m] = *(const short8*)&S[offA[m]];
#pragma unroll
    for (int n = 0; n < 4; ++n) bv[n] = *(const short8*)&S[offB[n]];

    __builtin_amdgcn_s_setprio(1);
#pragma unroll
    for (int m = 0; m < 4; ++m)
#pragma unroll
      for (int n = 0; n < 4; ++n)
        acc[m][n] = __builtin_amdgcn_mfma_f32_16x16x32_bf16(av[m], bv[n], acc[m][n], 0, 0, 0);
    __builtin_amdgcn_s_setprio(0);

    // certify tile t+1; keep later prefetches in flight (never drain mid-loop)
    if      (t + 3 < nk) { asm volatile("s_waitcnt vmcnt(4)" ::: "memory"); }
    else if (t + 2 < nk) { asm volatile("s_waitcnt vmcnt(2)" ::: "memory"); }
    else                 { asm volatile("s_waitcnt vmcnt(0)" ::: "memory"); }
    __builtin_amdgcn_s_barrier();
  }
#undef STAGE

  // C/D layout: col = lane&15, row = (lane>>4)*4 + reg  [m89-verified]
  if constexpr (MODE == 1) {
    const int row0 = bm * 256 + wm * 64, col0 = bn * 256 + wn * 64;
#pragma unroll
    for (int m = 0; m < 4; ++m)
#pragma unroll
      for (int n = 0; n < 4; ++n) {
        const int c  = col0 + n * 16 + lr;
        const int rb = row0 + m * 16 + lg * 4;
#pragma unroll
        for (int j = 0; j < 4; ++j) {
          const int r = rb + j;
          __builtin_nontemporal_store(acc[m][n][j] * Wt[r], &O[(size_t)r * N + c]);
        }
      }
  } else {
    // g/u exchange via LDS. Bank-spread perm: xo = lr*16 + (lg^((lr>>1)&3))*4
    // -> each quarter-wave covers 8 distinct bank-quads (2-way max = free).
    float* X = (float*)&lds[0][0];   // 8 g-waves x 4KB = 32KB (loop-dead)
    const int xo = lr * 16 + ((lg ^ ((lr >> 1) & 3)) * 4);
    const int row0 = bm * 256 + wm * 64, col0 = bn * 128 + wn * 64;
#pragma unroll
    for (int m = 0; m < 4; ++m) {
      __builtin_amdgcn_s_barrier();          // prev phase's reads done
      if (s == 0) {
#pragma unroll
        for (int n = 0; n < 4; ++n)
          *(f32x4*)&X[w * 1024 + n * 256 + xo] = acc[m][n];
      }
      __builtin_amdgcn_s_barrier();          // writes visible
      if (s == 1) {
#pragma unroll
        for (int n = 0; n < 4; ++n) {
          const f32x4 g4 = *(const f32x4*)&X[(w - 8) * 1024 + n * 256 + xo];
          const int c  = col0 + n * 16 + lr;
          const int rb = row0 + m * 16 + lg * 4;
#pragma unroll
          for (int j = 0; j < 4; ++j)
            G[(size_t)(rb + j) * N + c] = f2bf(silu(g4[j]) * acc[m][n][j]);
        }
      }
    }
  }
}

extern "C" void kernel_launch(void* const* d_in, const int* in_sizes, int n_in,
                              void* d_out, int out_size, void* d_ws, size_t ws_size,
                              hipStream_t stream) {
  const float* x   = (const float*)d_in[0];
  const float* Wg  = (const float*)d_in[1];
  const float* Wu  = (const float*)d_in[2];
  const float* Wd  = (const float*)d_in[3];
  const int*   top = (const int*)d_in[4];
  const float* wt  = (const float*)d_in[5];
  float* out = (float*)d_out;

  const size_t NE_X = (size_t)NSEL * HIDDEN;
  const size_t NE_W = (size_t)INTER * HIDDEN;
  if (ws_size < (NE_X + 4 * NE_W) * sizeof(uint16_t)) return;

  uint16_t* xs = (uint16_t*)d_ws;
  uint16_t* w1 = xs + NE_X;    // Wg bf16
  uint16_t* w2 = w1 + NE_W;    // Wu bf16
  uint16_t* w3 = w2 + NE_W;    // Wd bf16
  uint16_t* gh = w3 + NE_W;    // h bf16 [NSEL][INTER]

  const int NCVT = (int)(NE_W / 16384);   // 3584 blocks per weight (prep)
  const int NCVT_GU = (int)(NE_W / 65536);// 896 tail blocks (inside GU)
  const int ngGU = 16 * (INTER / 128);    // 1792
  const int ngDN = 16 * (HIDDEN / 256);   // 256

  // gather + Wg,Wu cvts (Wd cvt rides inside the GU launch)
  prep<<<NSEL + 2 * NCVT, 256, 0, stream>>>(x, top, xs, Wg, w1, Wu, w2, NCVT);

  // fused gate+up: h = silu(x Wg^T) * (x Wu^T) -> gh; tail: Wd -> w3
  gemm_f<0><<<ngGU + NCVT_GU, 1024, 0, stream>>>(xs, w1, w2, gh, nullptr, nullptr,
                                                 INTER, HIDDEN, ngGU, Wd, w3);
  // down + routing weight: out = (h Wd^T) * weight[:,None]
  gemm_f<1><<<ngDN, 1024, 0, stream>>>(gh, w3, nullptr, nullptr, out, wt,
                                       HIDDEN, INTER, ngDN, nullptr, nullptr);
}